// Round 1
// 1899.315 us; speedup vs baseline: 1.1882x; 1.1882x over previous
//
#include <hip/hip_runtime.h>

#define BB   256
#define TT   512
#define FF   8
#define HH   256
#define LL   4
#define OO   8
#define BETA 0.8f
#define THRV 1.0f

// d_out layout (floats): outputs | hidden | prev_obs | readout
#define OFF_OUT  0
#define OFF_HID  (BB*TT*OO)
#define OFF_PREV (OFF_HID + (size_t)BB*TT*LL*HH)
#define OFF_RO   (OFF_PREV + BB*TT*FF)

typedef float nf4 __attribute__((ext_vector_type(4)));

// Sparse row-sum over a contiguous LDS list of pre-scaled row offsets (h<<8).
// 2-deep software pipeline: batch k+1's list reads + global loads are issued
// before batch k's accumulate, so the LDS->L2 dependent chain overlaps.
// Tail batch is speculative (list is padded + pre-zeroed; stale entries are
// always valid in-bounds row offsets) and masked with cndmask selects.
__device__ __forceinline__ float scan_sum(const int* lst, int n, const float* __restrict__ Wb)
{
    float cc = 0.f;
    int j = 0;
    if (n >= 8) {
        int4 e0 = *(const int4*)(lst);
        int4 e1 = *(const int4*)(lst + 4);
        float w0 = Wb[e0.x], w1 = Wb[e0.y], w2 = Wb[e0.z], w3 = Wb[e0.w];
        float w4 = Wb[e1.x], w5 = Wb[e1.y], w6 = Wb[e1.z], w7 = Wb[e1.w];
        j = 8;
        while (j + 7 < n) {
            int4 f0 = *(const int4*)(lst + j);
            int4 f1 = *(const int4*)(lst + j + 4);
            float v0 = Wb[f0.x], v1 = Wb[f0.y], v2 = Wb[f0.z], v3 = Wb[f0.w];
            float v4 = Wb[f1.x], v5 = Wb[f1.y], v6 = Wb[f1.z], v7 = Wb[f1.w];
            cc += ((w0 + w1) + (w2 + w3)) + ((w4 + w5) + (w6 + w7));
            w0 = v0; w1 = v1; w2 = v2; w3 = v3;
            w4 = v4; w5 = v5; w6 = v6; w7 = v7;
            j += 8;
        }
        cc += ((w0 + w1) + (w2 + w3)) + ((w4 + w5) + (w6 + w7));
    }
    if (j < n) {
        int4 e0 = *(const int4*)(lst + j);
        int4 e1 = *(const int4*)(lst + j + 4);
        float w0 = Wb[e0.x], w1 = Wb[e0.y], w2 = Wb[e0.z], w3 = Wb[e0.w];
        float w4 = Wb[e1.x], w5 = Wb[e1.y], w6 = Wb[e1.z], w7 = Wb[e1.w];
        cc += (j + 0 < n ? w0 : 0.f) + (j + 1 < n ? w1 : 0.f)
            + (j + 2 < n ? w2 : 0.f) + (j + 3 < n ? w3 : 0.f)
            + (j + 4 < n ? w4 : 0.f) + (j + 5 < n ? w5 : 0.f)
            + (j + 6 < n ? w6 : 0.f) + (j + 7 < n ? w7 : 0.f);
    }
    return cc;
}

// LIF update + spike publish: ballot -> LDS atomicAdd gives this wave a
// contiguous base (segment order is irrelevant for a sum) -> list write.
// All pre-barrier: ONE barrier per layer instead of three.
#define UPDATE_PUBLISH(mreg, li, cval)                                          \
    {                                                                           \
        float reset_ = ((mreg) > THRV) ? THRV : 0.f;                            \
        (mreg) = BETA * (mreg) + (cval) - reset_;                               \
        int spk_ = ((mreg) > THRV) ? 1 : 0;                                     \
        __builtin_nontemporal_store((mreg), hrow + (li) * HH + h);              \
        unsigned long long bm_ = __ballot(spk_);                                \
        int base_ = 0;                                                          \
        if (lane == 0) base_ = atomicAdd(&s_total[li], __popcll(bm_));          \
        base_ = __shfl(base_, 0);                                               \
        if (spk_)                                                               \
            s_list[li][base_ + __popcll(bm_ & ((1ull << lane) - 1ull))] = h << 8;\
    }

__launch_bounds__(320, 1)
__global__ void snn_kernel(const float* __restrict__ x,
                           const float* __restrict__ hidden_in,
                           const float* __restrict__ readout_in,
                           const float* __restrict__ W1,
                           const float* __restrict__ b1,
                           const float* __restrict__ Wh,
                           const float* __restrict__ bh,
                           const float* __restrict__ Wout,
                           const float* __restrict__ bout,
                           float* __restrict__ out)
{
    // +8 pad per list so the speculative tail batch never reads OOB;
    // pre-zeroed, and stale entries are valid row offsets -> loads stay in Wh.
    __shared__ int                s_list[3][264];
    __shared__ int                s_total[3];
    __shared__ unsigned long long s_mask3[4];

    const int tid  = threadIdx.x;
    const int b    = blockIdx.x;
    const int lane = tid & 63;
    const int wave = tid >> 6;          // 0..3: h-owners, 4: readout wave
    const int h    = tid & (HH - 1);

    for (int i = tid; i < 3 * 264; i += 320) ((int*)s_list)[i] = 0;
    if (tid < 3) s_total[tid] = 0;
    if (tid < 4) s_mask3[tid] = 0ull;

    // prev_obs = x (pure copy), nontemporal
    {
        const nf4* xs = (const nf4*)(x + (size_t)b * TT * FF);
        nf4*       po = (nf4*)(out + OFF_PREV + (size_t)b * TT * FF);
        for (int i = tid; i < (TT * FF) / 4; i += 320)
            __builtin_nontemporal_store(xs[i], po + i);
    }

    float m0 = 0, m1 = 0, m2 = 0, m3 = 0;
    float w1c[FF];
    float b1c = 0, bhc0 = 0, bhc1 = 0, bhc2 = 0;
    if (tid < 256) {
        const size_t hb = (size_t)b * TT * LL * HH;
        m0 = hidden_in[hb + 0 * HH + h];
        m1 = hidden_in[hb + 1 * HH + h];
        m2 = hidden_in[hb + 2 * HH + h];
        m3 = hidden_in[hb + 3 * HH + h];
        #pragma unroll
        for (int f = 0; f < FF; ++f) w1c[f] = W1[f * HH + h];
        b1c  = b1[h];
        bhc0 = bh[0 * HH + h]; bhc1 = bh[1 * HH + h]; bhc2 = bh[2 * HH + h];
    }

    // wave 4: lane = (o, seg) pair; ro recurrence lives in lanes 0..7
    const int o8  = lane & 7;
    const int seg = lane >> 3;
    float ro = 0.f, boutc = 0.f;
    if (wave == 4 && lane < 8) {
        ro    = readout_in[(size_t)b * TT * OO + lane];
        boutc = bout[lane];
    }

    const float* xb  = x + (size_t)b * TT * FF;
    const float* Wb0 = Wh + h;
    const float* Wb1 = Wh + 1 * HH * HH + h;
    const float* Wb2 = Wh + 2 * HH * HH + h;
    float* hid_out = out + OFF_HID + (size_t)b * TT * LL * HH;
    float* out_o   = out + OFF_OUT + (size_t)b * TT * OO;
    float* out_r   = out + OFF_RO  + (size_t)b * TT * OO;

    nf4 xv0 = {0, 0, 0, 0}, xv1 = {0, 0, 0, 0};
    if (tid < 256) { xv0 = ((const nf4*)xb)[0]; xv1 = ((const nf4*)xb)[1]; }

    __syncthreads();

    #pragma unroll 1
    for (int t = 0; t < TT; ++t) {
        float* hrow = hid_out + (size_t)t * LL * HH;

        // ---- P1: input current from prefetched x, layer-0 update+publish ----
        if (tid < 256) {
            float c = b1c + xv0.x * w1c[0] + xv0.y * w1c[1] + xv0.z * w1c[2] + xv0.w * w1c[3]
                          + xv1.x * w1c[4] + xv1.y * w1c[5] + xv1.z * w1c[6] + xv1.w * w1c[7];
            UPDATE_PUBLISH(m0, 0, c);
        } else if (tid == 256) {
            s_total[2] = 0;   // written P3(t-1), read P4(t-1); safe to reset here
        }
        __syncthreads();      // B1

        // ---- P2: scan0 -> layer-1; wave4 overlaps readout of t-1 here ----
        if (tid < 256) {
            const int tn = (t + 1 < TT) ? t + 1 : t;       // x prefetch for t+1
            xv0 = ((const nf4*)(xb + tn * FF))[0];
            xv1 = ((const nf4*)(xb + tn * FF))[1];
            float c = bhc0 + scan_sum(s_list[0], s_total[0], Wb0);
            UPDATE_PUBLISH(m1, 1, c);
        } else if (t > 0) {
            // readout for t-1 from layer-3 ballot masks (published P4(t-1)).
            // s_mask3 is not rewritten until P4(t), so reads here are safe.
            unsigned sm = ((const unsigned*)s_mask3)[seg];
            float acc = 0.f;
            while (sm) {
                int r = __builtin_ctz(sm);
                sm &= sm - 1;
                acc += Wout[((seg << 5) + r) * OO + o8];
            }
            acc += __shfl_xor(acc, 8);
            acc += __shfl_xor(acc, 16);
            acc += __shfl_xor(acc, 32);
            if (lane < 8) {
                ro = BETA * ro + (acc + boutc);
                __builtin_nontemporal_store(ro, out_o + (t - 1) * OO + lane);
                __builtin_nontemporal_store(ro, out_r + (t - 1) * OO + lane);
            }
        }
        __syncthreads();      // B2

        // ---- P3: scan1 -> layer-2 ----
        if (tid < 256) {
            float c = bhc1 + scan_sum(s_list[1], s_total[1], Wb1);
            UPDATE_PUBLISH(m2, 2, c);
        } else if (tid == 256) {
            s_total[0] = 0;   // written P1, read P2; safe now
        }
        __syncthreads();      // B3

        // ---- P4: scan2 -> layer-3 update, publish ballot masks for wave4 ----
        if (tid < 256) {
            float c = bhc2 + scan_sum(s_list[2], s_total[2], Wb2);
            float reset_ = (m3 > THRV) ? THRV : 0.f;
            m3 = BETA * m3 + c - reset_;
            int spk_ = (m3 > THRV) ? 1 : 0;
            __builtin_nontemporal_store(m3, hrow + 3 * HH + h);
            unsigned long long bm_ = __ballot(spk_);
            if (lane == 0) s_mask3[wave] = bm_;
        } else if (tid == 256) {
            s_total[1] = 0;   // written P2, read P3; safe now
        }
        __syncthreads();      // B4
    }

    // final readout for t = TT-1 (masks published before the last B4)
    if (wave == 4) {
        unsigned sm = ((const unsigned*)s_mask3)[seg];
        float acc = 0.f;
        while (sm) {
            int r = __builtin_ctz(sm);
            sm &= sm - 1;
            acc += Wout[((seg << 5) + r) * OO + o8];
        }
        acc += __shfl_xor(acc, 8);
        acc += __shfl_xor(acc, 16);
        acc += __shfl_xor(acc, 32);
        if (lane < 8) {
            ro = BETA * ro + (acc + boutc);
            __builtin_nontemporal_store(ro, out_o + (TT - 1) * OO + lane);
            __builtin_nontemporal_store(ro, out_r + (TT - 1) * OO + lane);
        }
    }
}

extern "C" void kernel_launch(void* const* d_in, const int* in_sizes, int n_in,
                              void* d_out, int out_size, void* d_ws, size_t ws_size,
                              hipStream_t stream) {
    const float* x       = (const float*)d_in[0];
    const float* hidden  = (const float*)d_in[1];
    // d_in[2] = prev_obs (unused by the recurrence)
    const float* readout = (const float*)d_in[3];
    const float* W1      = (const float*)d_in[4];
    const float* b1      = (const float*)d_in[5];
    const float* Wh      = (const float*)d_in[6];
    const float* bh      = (const float*)d_in[7];
    const float* Wout    = (const float*)d_in[8];
    const float* bout    = (const float*)d_in[9];
    float* out = (float*)d_out;

    snn_kernel<<<dim3(BB), dim3(320), 0, stream>>>(
        x, hidden, readout, W1, b1, Wh, bh, Wout, bout, out);
}